// Round 4
// baseline (323.406 us; speedup 1.0000x reference)
//
#include <hip/hip_runtime.h>

typedef __bf16 bf16;
typedef __bf16 bf16x8 __attribute__((ext_vector_type(8)));
typedef float  f32x4  __attribute__((ext_vector_type(4)));

// Problem constants
#define NSPEC   512          // 256 pairs * 2
#define BOUT    9999         // GROUPS*3
#define K0A     10240        // BOUT padded to 8*20*64 (ksplit*kiters*BK)
#define N00     1024         // 1000 padded
#define N01     896          // 800 padded
#define N02     896
#define N03     448          // 400 padded (14*32)

// async global->LDS, 16B per lane; lds base must be wave-uniform (HW adds lane*16)
__device__ __forceinline__ void gload_lds16(const bf16* g, bf16* l) {
    auto* gp = reinterpret_cast<const __attribute__((address_space(1))) unsigned int*>(
        reinterpret_cast<uintptr_t>(g));
    auto* lp = reinterpret_cast<__attribute__((address_space(3))) unsigned int*>(
        reinterpret_cast<uintptr_t>(l));
    __builtin_amdgcn_global_load_lds(gp, lp, 16, 0, 0);
}

__device__ __forceinline__ float agent_load(const float* p) {
    return __hip_atomic_load(p, __ATOMIC_RELAXED, __HIP_MEMORY_SCOPE_AGENT);
}

// ---------------- transpose tile helper: src (K x N) fp32 -> dst (N0 x K0) bf16 ----------------
__device__ __forceinline__ void transpose_tile(const float* __restrict__ src,
                                               bf16* __restrict__ dst,
                                               int K, int N, int K0, int bx, int by) {
    __shared__ float tile[32][33];
    int n0 = bx * 32, k0 = by * 32;
    int t = threadIdx.x;
    {
        int kr = t >> 3, nc = (t & 7) * 4;
        int gk = k0 + kr;
#pragma unroll
        for (int e = 0; e < 4; ++e) {
            int gn = n0 + nc + e;
            tile[kr][nc + e] = (gk < K && gn < N) ? src[(size_t)gk * N + gn] : 0.0f;
        }
    }
    __syncthreads();
    {
        int nr = t >> 3, kc = (t & 7) * 4;
        bf16 v[4];
#pragma unroll
        for (int e = 0; e < 4; ++e) v[e] = (bf16)tile[kc + e][nr];
        *(ushort4*)&dst[(size_t)(n0 + nr) * K0 + k0 + kc] = *(ushort4*)v;
    }
}

// ---------------- prep: H0 bias init + all weight transposes + zero cosine accumulators ----------------
__global__ __launch_bounds__(256) void prep(const float* __restrict__ b0,
                                            const float* __restrict__ w0,
                                            const float* __restrict__ w1,
                                            const float* __restrict__ w2,
                                            const float* __restrict__ we,
                                            float* __restrict__ H0,
                                            bf16* __restrict__ B0t,
                                            bf16* __restrict__ B1t,
                                            bf16* __restrict__ B2t,
                                            bf16* __restrict__ BEt,
                                            float* __restrict__ psums,
                                            int* __restrict__ gcnt) {
    int b = blockIdx.x;
    if (b < 512) {                        // H0 <- broadcast b0 (512 x 1024)
        int u = b * 256 + threadIdx.x;
        int row = u >> 8, c = (u & 255) * 4;
        float4 v;
        v.x = (c + 0 < 1000) ? b0[c + 0] : 0.f;
        v.y = (c + 1 < 1000) ? b0[c + 1] : 0.f;
        v.z = (c + 2 < 1000) ? b0[c + 2] : 0.f;
        v.w = (c + 3 < 1000) ? b0[c + 3] : 0.f;
        *(float4*)&H0[(size_t)row * N00 + c] = v;
    } else if (b < 10752) {               // w0 -> B0t (1024 x 10240), 32 x 320 tiles
        int r = b - 512;
        transpose_tile(w0, B0t, BOUT, 1000, K0A, r & 31, r >> 5);
    } else if (b < 11648) {               // w1 -> B1t (896 x 1024), 28 x 32 tiles
        int r = b - 10752;
        transpose_tile(w1, B1t, 1000, 800, 1024, r % 28, r / 28);
    } else if (b < 12432) {               // w2 -> B2t (896 x 896), 28 x 28 tiles
        int r = b - 11648;
        transpose_tile(w2, B2t, 800, 800, 896, r % 28, r / 28);
    } else if (b < 12824) {               // we -> BEt (448 x 896), 14 x 28 tiles
        int r = b - 12432;
        transpose_tile(we, BEt, 800, 400, 896, r % 14, r / 14);
    } else {                              // zero cosine accumulators
        int t = threadIdx.x;
        if (t < 768) { psums[t] = 0.f; psums[t + 768] = 0.f; psums[t + 1536] = 0.f; }
        if (t == 0) *gcnt = 0;
    }
}

// ---------------- build_A: per-spectrum LDS scatter + binner_b add + bf16 convert ----------------
__global__ __launch_bounds__(512) void build_A(const float* __restrict__ mz,
                                               const float* __restrict__ inten,
                                               const float* __restrict__ bw,
                                               const float* __restrict__ bb,
                                               bf16* __restrict__ A,
                                               int* __restrict__ tileCnt) {
    __shared__ float sacc[K0A];
    const int spec = blockIdx.x;
    const int t = threadIdx.x;
    if (spec == 0 && t < 128) tileCnt[t] = 0;   // zero gemm0 completion counters
    // zero LDS accumulator
#pragma unroll
    for (int i = 0; i < 5; ++i)
        *(float4*)&sacc[(i * 512 + t) * 4] = float4{0.f, 0.f, 0.f, 0.f};
    __syncthreads();
    // scatter this spectrum's 512 peaks (LDS atomics)
    {
        float m = mz[(size_t)spec * 512 + t];
        float v = inten[(size_t)spec * 512 + t];
        bool mask = (m >= 0.0f) && (m < 1000.0f);
        int idx = (int)(m / 0.01f);             // IEEE div + trunc, matches astype(int32)
        idx = min(max(idx, 0), 99999);
        if (mask && idx < 99990) {
            int g = idx / 30;
            float val = sqrtf(v);               // inten ** 0.5
            const float* w = bw + (size_t)idx * 3;
            atomicAdd(&sacc[g * 3 + 0], val * w[0]);
            atomicAdd(&sacc[g * 3 + 1], val * w[1]);
            atomicAdd(&sacc[g * 3 + 2], val * w[2]);
        }
    }
    __syncthreads();
    // A[spec][:] = bf16(bb + sacc), zero pad beyond BOUT
    bf16* Arow = A + (size_t)spec * K0A;
#pragma unroll
    for (int i = 0; i < 5; ++i) {
        int c = (i * 512 + t) * 4;
        float4 s = *(const float4*)&sacc[c];
        bf16 o[4];
        o[0] = (bf16)((c + 0 < BOUT) ? bb[c + 0] + s.x : 0.f);
        o[1] = (bf16)((c + 1 < BOUT) ? bb[c + 1] + s.y : 0.f);
        o[2] = (bf16)((c + 2 < BOUT) ? bb[c + 2] + s.z : 0.f);
        o[3] = (bf16)((c + 3 < BOUT) ? bb[c + 3] + s.w : 0.f);
        *(ushort4*)&Arow[c] = *(ushort4*)o;
    }
}

// ---------------- GEMM0: 64x64xBK64, split-K=8 XCD-pinned, dbuf, fused relu+cvt completion ----------------
__global__ __launch_bounds__(256) void gemm0_splitk(const bf16* __restrict__ A,
                                                    const bf16* __restrict__ Bt,
                                                    float* __restrict__ C,
                                                    bf16* __restrict__ Cb,
                                                    int* __restrict__ tileCnt) {
    constexpr int K0 = K0A, KITERS = 20;
    __shared__ __align__(16) bf16 As[2][64 * 64];
    __shared__ __align__(16) bf16 Bs[2][64 * 64];
    const int bid = blockIdx.x;
    const int kp = bid & 7;                   // kp == XCD (round-robin dispatch)
    const int tile = bid >> 3;
    const int mt = tile & 7, nt = tile >> 3;
    const int tid = threadIdx.x, wave = tid >> 6, lane = tid & 63;
    const int wm = wave & 1, wn = wave >> 1;
    const int lrow = lane & 15, quad = lane >> 4;
    const int l8 = lane >> 3, lc = (lane & 7) * 8;

    const bf16* Ag = A  + (size_t)(mt * 64) * K0 + kp * KITERS * 64;
    const bf16* Bg = Bt + (size_t)(nt * 64) * K0 + kp * KITERS * 64;

    auto stage = [&](int buf, int kk) {
        const int k = kk * 64;
#pragma unroll
        for (int j = 0; j < 2; ++j) {
            int row = j * 32 + wave * 8;
            gload_lds16(Ag + (size_t)(row + l8) * K0 + k + lc, &As[buf][row * 64]);
            gload_lds16(Bg + (size_t)(row + l8) * K0 + k + lc, &Bs[buf][row * 64]);
        }
    };

    f32x4 acc[2][2] = {};
    stage(0, 0);
    for (int kk = 0; kk < KITERS; ++kk) {
        const int cur = kk & 1;
        __syncthreads();
        if (kk + 1 < KITERS) stage(cur ^ 1, kk + 1);
        bf16x8 af[2][2], bfr[2][2];
#pragma unroll
        for (int ks = 0; ks < 2; ++ks) {
#pragma unroll
            for (int im = 0; im < 2; ++im)
                af[ks][im] = *(const bf16x8*)&As[cur][(wm * 32 + im * 16 + lrow) * 64 + ks * 32 + quad * 8];
#pragma unroll
            for (int in = 0; in < 2; ++in)
                bfr[ks][in] = *(const bf16x8*)&Bs[cur][(wn * 32 + in * 16 + lrow) * 64 + ks * 32 + quad * 8];
        }
#pragma unroll
        for (int ks = 0; ks < 2; ++ks)
#pragma unroll
            for (int im = 0; im < 2; ++im)
#pragma unroll
                for (int in = 0; in < 2; ++in)
                    acc[im][in] = __builtin_amdgcn_mfma_f32_16x16x32_bf16(af[ks][im], bfr[ks][in], acc[im][in], 0, 0, 0);
    }
#pragma unroll
    for (int im = 0; im < 2; ++im) {
        int row0 = mt * 64 + wm * 32 + im * 16 + quad * 4;
#pragma unroll
        for (int in = 0; in < 2; ++in) {
            int col = nt * 64 + wn * 32 + in * 16 + lrow;
#pragma unroll
            for (int r = 0; r < 4; ++r)
                atomicAdd(&C[(size_t)(row0 + r) * N00 + col], acc[im][in][r]);
        }
    }
    // completion: last kp-block for this tile does relu + bf16 convert
    __threadfence();
    __syncthreads();
    __shared__ int is_last;
    if (tid == 0) is_last = (atomicAdd(&tileCnt[tile], 1) == 7) ? 1 : 0;
    __syncthreads();
    if (is_last) {
        __threadfence();
        for (int i = tid; i < 64 * 16; i += 256) {      // 64 rows x 16 float4
            int r = mt * 64 + (i >> 4);
            int c = nt * 64 + (i & 15) * 4;
            const float* src = &C[(size_t)r * N00 + c];
            bf16 o[4];
#pragma unroll
            for (int e = 0; e < 4; ++e) o[e] = (bf16)fmaxf(agent_load(src + e), 0.f);
            *(ushort4*)&Cb[(size_t)r * N00 + c] = *(ushort4*)o;
        }
    }
}

// ---------------- small GEMM: 32x32 tiles, BK=128, dbuf, fused bias+relu, bf16 out ----------------
__global__ __launch_bounds__(256) void gemm_small(const bf16* __restrict__ A,
                                                  const bf16* __restrict__ Bt,
                                                  const float* __restrict__ bias,
                                                  bf16* __restrict__ Ob,
                                                  int K0, int N0, int Nreal,
                                                  int kiters, int ntiles) {
    __shared__ __align__(16) bf16 As[2][32 * 128];
    __shared__ __align__(16) bf16 Bs[2][32 * 128];
    const int bid = blockIdx.x;
    const int mt = bid / ntiles, nt = bid % ntiles;
    const int tid = threadIdx.x, wave = tid >> 6, lane = tid & 63;
    const int wm = wave & 1, wn = wave >> 1;
    const int lrow = lane & 15, quad = lane >> 4;
    const int l4 = lane >> 4, lc = (lane & 15) * 8;

    const bf16* Ag = A  + (size_t)(mt * 32) * K0;
    const bf16* Bg = Bt + (size_t)(nt * 32) * K0;

    auto stage = [&](int buf, int kk) {
        const int k = kk * 128;
#pragma unroll
        for (int j = wave; j < 8; j += 4) {
            int row = j * 4;
            gload_lds16(Ag + (size_t)(row + l4) * K0 + k + lc, &As[buf][row * 128]);
            gload_lds16(Bg + (size_t)(row + l4) * K0 + k + lc, &Bs[buf][row * 128]);
        }
    };

    f32x4 acc = {};
    stage(0, 0);
    for (int kk = 0; kk < kiters; ++kk) {
        const int cur = kk & 1;
        __syncthreads();
        if (kk + 1 < kiters) stage(cur ^ 1, kk + 1);
#pragma unroll
        for (int ks = 0; ks < 4; ++ks) {
            bf16x8 af  = *(const bf16x8*)&As[cur][(wm * 16 + lrow) * 128 + ks * 32 + quad * 8];
            bf16x8 bfr = *(const bf16x8*)&Bs[cur][(wn * 16 + lrow) * 128 + ks * 32 + quad * 8];
            acc = __builtin_amdgcn_mfma_f32_16x16x32_bf16(af, bfr, acc, 0, 0, 0);
        }
    }
    int row0 = mt * 32 + wm * 16 + quad * 4;
    int col  = nt * 32 + wn * 16 + lrow;
    float bv = (col < Nreal) ? bias[col] : 0.f;
#pragma unroll
    for (int r = 0; r < 4; ++r) {
        float v = fmaxf(acc[r] + bv, 0.f);
        Ob[(size_t)(row0 + r) * N0 + col] = (bf16)v;
    }
}

// ---------------- last GEMM + fused cosine: partial dot/n1/n2 sums + last-block finalize ----------------
__global__ __launch_bounds__(256) void gemm_last(const bf16* __restrict__ A,
                                                 const bf16* __restrict__ Bt,
                                                 const float* __restrict__ bias,
                                                 float* __restrict__ psums,
                                                 int* __restrict__ gcnt,
                                                 float* __restrict__ out,
                                                 int K0, int kiters, int ntiles) {
    __shared__ __align__(16) bf16 As[2][32 * 128];
    __shared__ __align__(16) bf16 Bs[2][32 * 128];
    const int bid = blockIdx.x;
    const int mt = bid / ntiles, nt = bid % ntiles;
    const int tid = threadIdx.x, wave = tid >> 6, lane = tid & 63;
    const int wm = wave & 1, wn = wave >> 1;
    const int lrow = lane & 15, quad = lane >> 4;
    const int l4 = lane >> 4, lc = (lane & 15) * 8;

    const bf16* Ag = A  + (size_t)(mt * 32) * K0;
    const bf16* Bg = Bt + (size_t)(nt * 32) * K0;

    auto stage = [&](int buf, int kk) {
        const int k = kk * 128;
#pragma unroll
        for (int j = wave; j < 8; j += 4) {
            int row = j * 4;
            gload_lds16(Ag + (size_t)(row + l4) * K0 + k + lc, &As[buf][row * 128]);
            gload_lds16(Bg + (size_t)(row + l4) * K0 + k + lc, &Bs[buf][row * 128]);
        }
    };

    f32x4 acc = {};
    stage(0, 0);
    for (int kk = 0; kk < kiters; ++kk) {
        const int cur = kk & 1;
        __syncthreads();
        if (kk + 1 < kiters) stage(cur ^ 1, kk + 1);
#pragma unroll
        for (int ks = 0; ks < 4; ++ks) {
            bf16x8 af  = *(const bf16x8*)&As[cur][(wm * 16 + lrow) * 128 + ks * 32 + quad * 8];
            bf16x8 bfr = *(const bf16x8*)&Bs[cur][(wn * 16 + lrow) * 128 + ks * 32 + quad * 8];
            acc = __builtin_amdgcn_mfma_f32_16x16x32_bf16(af, bfr, acc, 0, 0, 0);
        }
    }
    // epilogue: e-values, per-pair partial sums over this lane's col
    int rowbase = mt * 32 + wm * 16 + quad * 4;        // even (quad*4)
    int col     = nt * 32 + wn * 16 + lrow;
    bool valid  = (col < 400);
    float bv = valid ? bias[col] : 0.f;
    float v[4];
#pragma unroll
    for (int r = 0; r < 4; ++r) v[r] = valid ? (acc[r] + bv) : 0.f;
    int p0 = rowbase >> 1;                              // pairs p0, p0+1
    float sums[6] = {v[0] * v[1], v[0] * v[0], v[1] * v[1],
                     v[2] * v[3], v[2] * v[2], v[3] * v[3]};
#pragma unroll
    for (int off = 1; off < 16; off <<= 1)
#pragma unroll
        for (int s = 0; s < 6; ++s) sums[s] += __shfl_xor(sums[s], off);
    if (lrow == 0) {
#pragma unroll
        for (int s = 0; s < 3; ++s) {
            atomicAdd(&psums[(p0 + 0) * 3 + s], sums[s]);
            atomicAdd(&psums[(p0 + 1) * 3 + s], sums[3 + s]);
        }
    }
    // completion: last block finalizes all 256 outputs
    __threadfence();
    __syncthreads();
    __shared__ int is_last;
    if (tid == 0) is_last = (atomicAdd(gcnt, 1) == 16 * 14 - 1) ? 1 : 0;
    __syncthreads();
    if (is_last) {
        __threadfence();
        if (tid < 256) {
            float d  = agent_load(&psums[tid * 3 + 0]);
            float s1 = agent_load(&psums[tid * 3 + 1]);
            float s2 = agent_load(&psums[tid * 3 + 2]);
            float n1 = fmaxf(sqrtf(s1), 1e-6f);
            float n2 = fmaxf(sqrtf(s2), 1e-6f);
            out[tid] = d / (n1 * n2);
        }
    }
}

extern "C" void kernel_launch(void* const* d_in, const int* in_sizes, int n_in,
                              void* d_out, int out_size, void* d_ws, size_t ws_size,
                              hipStream_t stream) {
    const float* mz    = (const float*)d_in[0];
    const float* inten = (const float*)d_in[1];
    const float* bw    = (const float*)d_in[2];
    const float* bb    = (const float*)d_in[3];
    const float* w0    = (const float*)d_in[4];
    const float* b0    = (const float*)d_in[5];
    const float* w1    = (const float*)d_in[6];
    const float* b1    = (const float*)d_in[7];
    const float* w2    = (const float*)d_in[8];
    const float* b2    = (const float*)d_in[9];
    const float* we    = (const float*)d_in[10];
    const float* be    = (const float*)d_in[11];
    float* out = (float*)d_out;

    char* ws = (char*)d_ws;
    size_t off = 0;
    auto alloc = [&](size_t bytes) { char* p = ws + off; off += (bytes + 255) & ~(size_t)255; return p; };
    bf16*  A    = (bf16*) alloc((size_t)NSPEC * K0A * 2);
    bf16*  B0t  = (bf16*) alloc((size_t)N00 * K0A * 2);
    bf16*  B1t  = (bf16*) alloc((size_t)N01 * 1024 * 2);
    bf16*  B2t  = (bf16*) alloc((size_t)N02 * 896 * 2);
    bf16*  BEt  = (bf16*) alloc((size_t)N03 * 896 * 2);
    float* H0   = (float*)alloc((size_t)NSPEC * N00 * 4);
    bf16*  H0b  = (bf16*) alloc((size_t)NSPEC * N00 * 2);
    bf16*  H1b  = (bf16*) alloc((size_t)NSPEC * N01 * 2);
    bf16*  H2b  = (bf16*) alloc((size_t)NSPEC * N02 * 2);
    float* psums = (float*)alloc(256 * 3 * 4 + 2560 * 4);  // 768 sums (+slack, prep zeroes 2304)
    int*   tileCnt = (int*)alloc(128 * 4);
    int*   gcnt    = (int*)alloc(4);

    // 1: H0 bias init + weight transposes + zero cosine accumulators
    prep<<<12825, 256, 0, stream>>>(b0, w0, w1, w2, we, H0, B0t, B1t, B2t, BEt, psums, gcnt);
    // 2: per-spectrum LDS scatter + binner bias + bf16 convert (also zeroes tileCnt)
    build_A<<<512, 512, 0, stream>>>(mz, inten, bw, bb, A, tileCnt);
    // 3: big GEMM, split-K=8 XCD-pinned, fused relu via completion counter
    gemm0_splitk<<<1024, 256, 0, stream>>>(A, B0t, H0, H0b, tileCnt);
    // 4-5: small fused GEMMs (bias+relu+bf16)
    gemm_small<<<448, 256, 0, stream>>>(H0b, B1t, b1, H1b, 1024, N01, 800, 8, 28);
    gemm_small<<<448, 256, 0, stream>>>(H1b, B2t, b2, H2b, 896,  N02, 800, 7, 28);
    // 6: last GEMM + fused cosine
    gemm_last<<<224, 256, 0, stream>>>(H2b, BEt, be, psums, gcnt, out, 896, 7, 14);
}

// Round 5
// 180.751 us; speedup vs baseline: 1.7892x; 1.7892x over previous
//
#include <hip/hip_runtime.h>

typedef __bf16 bf16;
typedef __bf16 bf16x8 __attribute__((ext_vector_type(8)));
typedef float  f32x4  __attribute__((ext_vector_type(4)));

// Problem constants
#define NSPEC   512          // 256 pairs * 2
#define BOUT    9999         // GROUPS*3
#define K0A     10240        // BOUT padded to 8*20*64 (ksplit*kiters*BK)
#define N00     1024         // 1000 padded
#define N01     896          // 800 padded
#define N02     896
#define N03     448          // 400 padded (14*32)

// async global->LDS, 16B per lane; lds base must be wave-uniform (HW adds lane*16)
__device__ __forceinline__ void gload_lds16(const bf16* g, bf16* l) {
    auto* gp = reinterpret_cast<const __attribute__((address_space(1))) unsigned int*>(
        reinterpret_cast<uintptr_t>(g));
    auto* lp = reinterpret_cast<__attribute__((address_space(3))) unsigned int*>(
        reinterpret_cast<uintptr_t>(l));
    __builtin_amdgcn_global_load_lds(gp, lp, 16, 0, 0);
}

// ---------------- transpose tile helper: src (K x N) fp32 -> dst (N0 x K0) bf16 ----------------
__device__ __forceinline__ void transpose_tile(const float* __restrict__ src,
                                               bf16* __restrict__ dst,
                                               int K, int N, int K0, int bx, int by) {
    __shared__ float tile[32][33];
    int n0 = bx * 32, k0 = by * 32;
    int t = threadIdx.x;
    {
        int kr = t >> 3, nc = (t & 7) * 4;
        int gk = k0 + kr;
#pragma unroll
        for (int e = 0; e < 4; ++e) {
            int gn = n0 + nc + e;
            tile[kr][nc + e] = (gk < K && gn < N) ? src[(size_t)gk * N + gn] : 0.0f;
        }
    }
    __syncthreads();
    {
        int nr = t >> 3, kc = (t & 7) * 4;
        bf16 v[4];
#pragma unroll
        for (int e = 0; e < 4; ++e) v[e] = (bf16)tile[kc + e][nr];
        *(ushort4*)&dst[(size_t)(n0 + nr) * K0 + k0 + kc] = *(ushort4*)v;
    }
}

// ---------------- prep: H0 bias init + all weight transposes ----------------
__global__ __launch_bounds__(256) void prep(const float* __restrict__ b0,
                                            const float* __restrict__ w0,
                                            const float* __restrict__ w1,
                                            const float* __restrict__ w2,
                                            const float* __restrict__ we,
                                            float* __restrict__ H0,
                                            bf16* __restrict__ B0t,
                                            bf16* __restrict__ B1t,
                                            bf16* __restrict__ B2t,
                                            bf16* __restrict__ BEt) {
    int b = blockIdx.x;
    if (b < 512) {                        // H0 <- broadcast b0 (512 x 1024)
        int u = b * 256 + threadIdx.x;
        int row = u >> 8, c = (u & 255) * 4;
        float4 v;
        v.x = (c + 0 < 1000) ? b0[c + 0] : 0.f;
        v.y = (c + 1 < 1000) ? b0[c + 1] : 0.f;
        v.z = (c + 2 < 1000) ? b0[c + 2] : 0.f;
        v.w = (c + 3 < 1000) ? b0[c + 3] : 0.f;
        *(float4*)&H0[(size_t)row * N00 + c] = v;
    } else if (b < 10752) {               // w0 -> B0t (1024 x 10240), 32 x 320 tiles
        int r = b - 512;
        transpose_tile(w0, B0t, BOUT, 1000, K0A, r & 31, r >> 5);
    } else if (b < 11648) {               // w1 -> B1t (896 x 1024), 28 x 32 tiles
        int r = b - 10752;
        transpose_tile(w1, B1t, 1000, 800, 1024, r % 28, r / 28);
    } else if (b < 12432) {               // w2 -> B2t (896 x 896), 28 x 28 tiles
        int r = b - 11648;
        transpose_tile(w2, B2t, 800, 800, 896, r % 28, r / 28);
    } else {                              // we -> BEt (448 x 896), 14 x 28 tiles
        int r = b - 12432;
        transpose_tile(we, BEt, 800, 400, 896, r % 14, r / 14);
    }
}

// ---------------- build_A: per-spectrum LDS scatter + binner_b add + bf16 convert ----------------
__global__ __launch_bounds__(512) void build_A(const float* __restrict__ mz,
                                               const float* __restrict__ inten,
                                               const float* __restrict__ bw,
                                               const float* __restrict__ bb,
                                               bf16* __restrict__ A) {
    __shared__ float sacc[K0A];
    const int spec = blockIdx.x;
    const int t = threadIdx.x;
    // zero LDS accumulator
#pragma unroll
    for (int i = 0; i < 5; ++i)
        *(float4*)&sacc[(i * 512 + t) * 4] = float4{0.f, 0.f, 0.f, 0.f};
    __syncthreads();
    // scatter this spectrum's 512 peaks (LDS atomics)
    {
        float m = mz[(size_t)spec * 512 + t];
        float v = inten[(size_t)spec * 512 + t];
        bool mask = (m >= 0.0f) && (m < 1000.0f);
        int idx = (int)(m / 0.01f);             // IEEE div + trunc, matches astype(int32)
        idx = min(max(idx, 0), 99999);
        if (mask && idx < 99990) {
            int g = idx / 30;
            float val = sqrtf(v);               // inten ** 0.5
            const float* w = bw + (size_t)idx * 3;
            atomicAdd(&sacc[g * 3 + 0], val * w[0]);
            atomicAdd(&sacc[g * 3 + 1], val * w[1]);
            atomicAdd(&sacc[g * 3 + 2], val * w[2]);
        }
    }
    __syncthreads();
    // A[spec][:] = bf16(bb + sacc), zero pad beyond BOUT
    bf16* Arow = A + (size_t)spec * K0A;
#pragma unroll
    for (int i = 0; i < 5; ++i) {
        int c = (i * 512 + t) * 4;
        float4 s = *(const float4*)&sacc[c];
        bf16 o[4];
        o[0] = (bf16)((c + 0 < BOUT) ? bb[c + 0] + s.x : 0.f);
        o[1] = (bf16)((c + 1 < BOUT) ? bb[c + 1] + s.y : 0.f);
        o[2] = (bf16)((c + 2 < BOUT) ? bb[c + 2] + s.z : 0.f);
        o[3] = (bf16)((c + 3 < BOUT) ? bb[c + 3] + s.w : 0.f);
        *(ushort4*)&Arow[c] = *(ushort4*)o;
    }
}

// ---------------- GEMM0: 64x64xBK64, split-K=8 XCD-pinned, dbuf, atomic fp32 epilogue ----------------
// NO device fences here — R4 showed per-block __threadfence costs ~0.17us x 1024 blocks.
__global__ __launch_bounds__(256) void gemm0_splitk(const bf16* __restrict__ A,
                                                    const bf16* __restrict__ Bt,
                                                    float* __restrict__ C) {
    constexpr int K0 = K0A, KITERS = 20;
    __shared__ __align__(16) bf16 As[2][64 * 64];
    __shared__ __align__(16) bf16 Bs[2][64 * 64];
    const int bid = blockIdx.x;
    const int kp = bid & 7;                   // kp == XCD (round-robin dispatch)
    const int tile = bid >> 3;
    const int mt = tile & 7, nt = tile >> 3;
    const int tid = threadIdx.x, wave = tid >> 6, lane = tid & 63;
    const int wm = wave & 1, wn = wave >> 1;
    const int lrow = lane & 15, quad = lane >> 4;
    const int l8 = lane >> 3, lc = (lane & 7) * 8;

    const bf16* Ag = A  + (size_t)(mt * 64) * K0 + kp * KITERS * 64;
    const bf16* Bg = Bt + (size_t)(nt * 64) * K0 + kp * KITERS * 64;

    auto stage = [&](int buf, int kk) {
        const int k = kk * 64;
#pragma unroll
        for (int j = 0; j < 2; ++j) {
            int row = j * 32 + wave * 8;
            gload_lds16(Ag + (size_t)(row + l8) * K0 + k + lc, &As[buf][row * 64]);
            gload_lds16(Bg + (size_t)(row + l8) * K0 + k + lc, &Bs[buf][row * 64]);
        }
    };

    f32x4 acc[2][2] = {};
    stage(0, 0);
    for (int kk = 0; kk < KITERS; ++kk) {
        const int cur = kk & 1;
        __syncthreads();                      // buf[cur] drained (vmcnt0 at barrier)
        if (kk + 1 < KITERS) stage(cur ^ 1, kk + 1);  // prefetch overlaps compute
        bf16x8 af[2][2], bfr[2][2];
#pragma unroll
        for (int ks = 0; ks < 2; ++ks) {
#pragma unroll
            for (int im = 0; im < 2; ++im)
                af[ks][im] = *(const bf16x8*)&As[cur][(wm * 32 + im * 16 + lrow) * 64 + ks * 32 + quad * 8];
#pragma unroll
            for (int in = 0; in < 2; ++in)
                bfr[ks][in] = *(const bf16x8*)&Bs[cur][(wn * 32 + in * 16 + lrow) * 64 + ks * 32 + quad * 8];
        }
#pragma unroll
        for (int ks = 0; ks < 2; ++ks)
#pragma unroll
            for (int im = 0; im < 2; ++im)
#pragma unroll
                for (int in = 0; in < 2; ++in)
                    acc[im][in] = __builtin_amdgcn_mfma_f32_16x16x32_bf16(af[ks][im], bfr[ks][in], acc[im][in], 0, 0, 0);
    }
#pragma unroll
    for (int im = 0; im < 2; ++im) {
        int row0 = mt * 64 + wm * 32 + im * 16 + quad * 4;
#pragma unroll
        for (int in = 0; in < 2; ++in) {
            int col = nt * 64 + wn * 32 + in * 16 + lrow;
#pragma unroll
            for (int r = 0; r < 4; ++r)
                atomicAdd(&C[(size_t)(row0 + r) * N00 + col], acc[im][in][r]);
        }
    }
}

// ---------------- relu + cvt to bf16, vectorized ----------------
__global__ __launch_bounds__(256) void relu_cvt4(const float* __restrict__ H,
                                                 bf16* __restrict__ Hb) {
    size_t t = (size_t)(blockIdx.x * 256 + threadIdx.x) * 4;
    float4 v = *(const float4*)&H[t];
    bf16 o[4] = {(bf16)fmaxf(v.x, 0.f), (bf16)fmaxf(v.y, 0.f),
                 (bf16)fmaxf(v.z, 0.f), (bf16)fmaxf(v.w, 0.f)};
    *(ushort4*)&Hb[t] = *(ushort4*)o;
}

// ---------------- small GEMM: 32x32 tiles, BK=128, dbuf, fused bias(+relu) epilogue ----------------
template <bool RELU, bool F32OUT>
__global__ __launch_bounds__(256) void gemm_small(const bf16* __restrict__ A,
                                                  const bf16* __restrict__ Bt,
                                                  const float* __restrict__ bias,
                                                  bf16* __restrict__ Ob,
                                                  float* __restrict__ Of,
                                                  int K0, int N0, int Nreal,
                                                  int kiters, int ntiles) {
    __shared__ __align__(16) bf16 As[2][32 * 128];
    __shared__ __align__(16) bf16 Bs[2][32 * 128];
    const int bid = blockIdx.x;
    const int mt = bid / ntiles, nt = bid % ntiles;
    const int tid = threadIdx.x, wave = tid >> 6, lane = tid & 63;
    const int wm = wave & 1, wn = wave >> 1;
    const int lrow = lane & 15, quad = lane >> 4;
    const int l4 = lane >> 4, lc = (lane & 15) * 8;

    const bf16* Ag = A  + (size_t)(mt * 32) * K0;
    const bf16* Bg = Bt + (size_t)(nt * 32) * K0;

    auto stage = [&](int buf, int kk) {
        const int k = kk * 128;
#pragma unroll
        for (int j = wave; j < 8; j += 4) {
            int row = j * 4;
            gload_lds16(Ag + (size_t)(row + l4) * K0 + k + lc, &As[buf][row * 128]);
            gload_lds16(Bg + (size_t)(row + l4) * K0 + k + lc, &Bs[buf][row * 128]);
        }
    };

    f32x4 acc = {};
    stage(0, 0);
    for (int kk = 0; kk < kiters; ++kk) {
        const int cur = kk & 1;
        __syncthreads();
        if (kk + 1 < kiters) stage(cur ^ 1, kk + 1);
#pragma unroll
        for (int ks = 0; ks < 4; ++ks) {
            bf16x8 af  = *(const bf16x8*)&As[cur][(wm * 16 + lrow) * 128 + ks * 32 + quad * 8];
            bf16x8 bfr = *(const bf16x8*)&Bs[cur][(wn * 16 + lrow) * 128 + ks * 32 + quad * 8];
            acc = __builtin_amdgcn_mfma_f32_16x16x32_bf16(af, bfr, acc, 0, 0, 0);
        }
    }
    int row0 = mt * 32 + wm * 16 + quad * 4;
    int col  = nt * 32 + wn * 16 + lrow;
    float bv = (col < Nreal) ? bias[col] : 0.f;
#pragma unroll
    for (int r = 0; r < 4; ++r) {
        float v = acc[r] + bv;
        if (RELU) v = fmaxf(v, 0.f);
        if (F32OUT) Of[(size_t)(row0 + r) * N0 + col] = v;
        else        Ob[(size_t)(row0 + r) * N0 + col] = (bf16)v;
    }
}

// ---------------- cosine similarity over pairs ----------------
__global__ __launch_bounds__(64) void cosine_k(const float* __restrict__ E,
                                               float* __restrict__ out) {
    int b = blockIdx.x;
    int lane = threadIdx.x;
    const float* e1 = E + (size_t)(2 * b) * N03;
    const float* e2 = e1 + N03;
    float dot = 0.f, s1 = 0.f, s2 = 0.f;
#pragma unroll
    for (int i = lane; i < N03; i += 64) {    // pad cols are exactly 0
        float a = e1[i], c = e2[i];
        dot += a * c; s1 += a * a; s2 += c * c;
    }
#pragma unroll
    for (int off = 32; off; off >>= 1) {
        dot += __shfl_down(dot, off);
        s1  += __shfl_down(s1, off);
        s2  += __shfl_down(s2, off);
    }
    if (lane == 0) {
        float n1 = fmaxf(sqrtf(s1), 1e-6f);
        float n2 = fmaxf(sqrtf(s2), 1e-6f);
        out[b] = dot / (n1 * n2);
    }
}

extern "C" void kernel_launch(void* const* d_in, const int* in_sizes, int n_in,
                              void* d_out, int out_size, void* d_ws, size_t ws_size,
                              hipStream_t stream) {
    const float* mz    = (const float*)d_in[0];
    const float* inten = (const float*)d_in[1];
    const float* bw    = (const float*)d_in[2];
    const float* bb    = (const float*)d_in[3];
    const float* w0    = (const float*)d_in[4];
    const float* b0    = (const float*)d_in[5];
    const float* w1    = (const float*)d_in[6];
    const float* b1    = (const float*)d_in[7];
    const float* w2    = (const float*)d_in[8];
    const float* b2    = (const float*)d_in[9];
    const float* we    = (const float*)d_in[10];
    const float* be    = (const float*)d_in[11];
    float* out = (float*)d_out;

    char* ws = (char*)d_ws;
    size_t off = 0;
    auto alloc = [&](size_t bytes) { char* p = ws + off; off += (bytes + 255) & ~(size_t)255; return p; };
    bf16*  A    = (bf16*) alloc((size_t)NSPEC * K0A * 2);
    bf16*  B0t  = (bf16*) alloc((size_t)N00 * K0A * 2);
    bf16*  B1t  = (bf16*) alloc((size_t)N01 * 1024 * 2);
    bf16*  B2t  = (bf16*) alloc((size_t)N02 * 896 * 2);
    bf16*  BEt  = (bf16*) alloc((size_t)N03 * 896 * 2);
    float* H0   = (float*)alloc((size_t)NSPEC * N00 * 4);
    bf16*  H0b  = (bf16*) alloc((size_t)NSPEC * N00 * 2);
    bf16*  H1b  = (bf16*) alloc((size_t)NSPEC * N01 * 2);
    bf16*  H2b  = (bf16*) alloc((size_t)NSPEC * N02 * 2);
    float* E    = (float*)alloc((size_t)NSPEC * N03 * 4);

    // 1: H0 bias init + weight transposes
    prep<<<12824, 256, 0, stream>>>(b0, w0, w1, w2, we, H0, B0t, B1t, B2t, BEt);
    // 2: per-spectrum LDS scatter + binner bias + bf16 convert
    build_A<<<512, 512, 0, stream>>>(mz, inten, bw, bb, A);
    // 3: big GEMM, split-K=8 XCD-pinned, atomic accumulate onto bias-init'd H0
    gemm0_splitk<<<1024, 256, 0, stream>>>(A, B0t, H0);
    // 4: relu + bf16 convert
    relu_cvt4<<<512, 256, 0, stream>>>(H0, H0b);
    // 5-6: small fused GEMMs (bias+relu+bf16)
    gemm_small<true,  false><<<448, 256, 0, stream>>>(H0b, B1t, b1, H1b, nullptr, 1024, N01, 800, 8, 28);
    gemm_small<true,  false><<<448, 256, 0, stream>>>(H1b, B2t, b2, H2b, nullptr, 896,  N02, 800, 7, 28);
    // 7: last GEMM -> fp32 E
    gemm_small<false, true ><<<224, 256, 0, stream>>>(H2b, BEt, be, nullptr, E, 896, N03, 400, 7, 14);
    // 8: cosine
    cosine_k<<<256, 64, 0, stream>>>(E, out);
}